// Round 1
// baseline (285.210 us; speedup 1.0000x reference)
//
#include <hip/hip_runtime.h>
#include <type_traits>
#include <utility>

#define NQ 10
#define N_DEPTH 5
#define DIM 1024
#define BATCH 16384
#define IN_DIM 784
#define NGATES 50

// ---------------------------------------------------------------------------
// Compile-time mask tables: CNOTs absorbed into GF(2)-linear index transform.
// Stored array A[m] represents logical basis state f(m); bit i of f(m) =
// parity(m & v[i]); flipping logical bit i maps m -> m ^ p[i].
// CNOT(c,t): v[t] ^= v[c]; p[c] ^= p[t].
// ---------------------------------------------------------------------------
struct MaskTab {
  unsigned v[NGATES];
  unsigned p[NGATES];
  unsigned vz0, vz1;
};

constexpr MaskTab make_masks() {
  MaskTab t{};
  unsigned v[NQ], p[NQ];
  for (int i = 0; i < NQ; ++i) { v[i] = 1u << (9 - i); p[i] = 1u << (9 - i); }
  for (int d = 0; d < N_DEPTH; ++d) {
    for (int i = 0; i < NQ; ++i) {      // CNOT ring: control i, target (i+1)%NQ
      int c = i, tt = (i + 1) % NQ;
      v[tt] ^= v[c];
      p[c]  ^= p[tt];
    }
    for (int i = 0; i < NQ; ++i) {      // Rot gates of this layer use these masks
      t.v[d * NQ + i] = v[i];
      t.p[d * NQ + i] = p[i];
    }
  }
  t.vz0 = v[0];  // final readout masks for <Z_0>, <Z_1>
  t.vz1 = v[1];
  return t;
}

constexpr MaskTab MT = make_masks();

template <int I, int N, typename F>
__device__ __forceinline__ void static_for(F&& f) {
  if constexpr (I < N) {
    f(std::integral_constant<int, I>{});
    static_for<I + 1, N>(static_cast<F&&>(f));
  }
}

// ---------------------------------------------------------------------------
// One wave = one sample. State: 1024 complex amps, 16 complex per lane in
// registers, index m = (r << 6) | lane.
// ---------------------------------------------------------------------------
__global__ __launch_bounds__(256) void qcl_sim(const float* __restrict__ x,
                                               const float* __restrict__ w,
                                               const int* __restrict__ y,
                                               float* __restrict__ losses) {
  __shared__ float UL[NGATES][8];

  const int tid = threadIdx.x;
  if (tid < NGATES) {
    // qml.Rot(phi, theta, omega) = RZ(omega) RY(theta) RZ(phi)
    float phi = w[tid * 3 + 0], th = w[tid * 3 + 1], om = w[tid * 3 + 2];
    float ct = cosf(th * 0.5f), st = sinf(th * 0.5f);
    float a = (phi + om) * 0.5f, b = (phi - om) * 0.5f;
    float cA = cosf(a), sA = sinf(a), cB = cosf(b), sB = sinf(b);
    UL[tid][0] =  ct * cA; UL[tid][1] = -ct * sA;   // m00 = e^{-ia} c
    UL[tid][2] = -st * cB; UL[tid][3] = -st * sB;   // m01 = -e^{+ib} s
    UL[tid][4] =  st * cB; UL[tid][5] = -st * sB;   // m10 = e^{-ib} s
    UL[tid][6] =  ct * cA; UL[tid][7] =  ct * sA;   // m11 = e^{+ia} c
  }
  __syncthreads();

  const int wave = tid >> 6;
  const int lane = tid & 63;
  const int sample = blockIdx.x * 4 + wave;

  // ---- amplitude embedding (unnormalized; norm folded into readout) ----
  const float* xr = x + (size_t)sample * IN_DIM;
  float are[16], aim[16];
#pragma unroll
  for (int r = 0; r < 16; ++r) { are[r] = 0.0f; aim[r] = 0.0f; }
#pragma unroll
  for (int r = 0; r < 12; ++r) are[r] = xr[r * 64 + lane];   // 768 coalesced
  if (lane < 16) are[12] = xr[768 + lane];                   // tail 784-768=16

  // ---- 50 Rot gates on generalized qubits (CNOTs folded into masks) ----
  static_for<0, NGATES>([&](auto G_) {
    constexpr int G = decltype(G_)::value;
    constexpr unsigned v = MT.v[G];
    constexpr unsigned p = MT.p[G];
    constexpr unsigned vl = v & 63u, vr = (v >> 6) & 15u;
    constexpr unsigned pl = p & 63u, pr = (p >> 6) & 15u;

    const float u00r = UL[G][0], u00i = UL[G][1];
    const float u01r = UL[G][2], u01i = UL[G][3];
    const float u10r = UL[G][4], u10i = UL[G][5];
    const float u11r = UL[G][6], u11i = UL[G][7];

    // lane-level bit of readout mask; per-register static complement
    const bool bl = (__builtin_popcount(lane & (int)vl) & 1) != 0;
    // coefficient sets indexed by static per-register parity s:
    // effective bit b = bl ^ s; new = U[b][b]*own + U[b][!b]*partner
    float cor[2], coi[2], cpr[2], cpi[2];
    cor[0] = bl ? u11r : u00r;  coi[0] = bl ? u11i : u00i;
    cpr[0] = bl ? u10r : u01r;  cpi[0] = bl ? u10i : u01i;
    cor[1] = bl ? u00r : u11r;  coi[1] = bl ? u00i : u11i;
    cpr[1] = bl ? u01r : u10r;  cpi[1] = bl ? u01i : u10i;

    if constexpr (pr == 0) {
      // partner in same register, different lane
      static_for<0, 16>([&](auto R_) {
        constexpr int r = decltype(R_)::value;
        constexpr int s = __builtin_popcount(r & (int)vr) & 1;
        float o_r = are[r], o_i = aim[r];
        float q_r = __shfl_xor(o_r, (int)pl);
        float q_i = __shfl_xor(o_i, (int)pl);
        are[r] = cor[s] * o_r - coi[s] * o_i + cpr[s] * q_r - cpi[s] * q_i;
        aim[r] = cor[s] * o_i + coi[s] * o_r + cpr[s] * q_i + cpi[s] * q_r;
      });
    } else {
      // partner in register r^pr (and lane^pl if pl!=0); process pairs once
      static_for<0, 16>([&](auto R_) {
        constexpr int r = decltype(R_)::value;
        constexpr int r2 = r ^ (int)pr;
        if constexpr (r < r2) {
          constexpr int s0 = __builtin_popcount(r & (int)vr) & 1;
          constexpr int s1 = __builtin_popcount(r2 & (int)vr) & 1;
          float o0r = are[r],  o0i = aim[r];
          float o1r = are[r2], o1i = aim[r2];
          float p0r, p0i, p1r, p1i;
          if constexpr (pl != 0) {
            p0r = __shfl_xor(o1r, (int)pl); p0i = __shfl_xor(o1i, (int)pl);
            p1r = __shfl_xor(o0r, (int)pl); p1i = __shfl_xor(o0i, (int)pl);
          } else {
            p0r = o1r; p0i = o1i;
            p1r = o0r; p1i = o0i;
          }
          are[r]  = cor[s0] * o0r - coi[s0] * o0i + cpr[s0] * p0r - cpi[s0] * p0i;
          aim[r]  = cor[s0] * o0i + coi[s0] * o0r + cpr[s0] * p0i + cpi[s0] * p0r;
          are[r2] = cor[s1] * o1r - coi[s1] * o1i + cpr[s1] * p1r - cpi[s1] * p1i;
          aim[r2] = cor[s1] * o1i + coi[s1] * o1r + cpr[s1] * p1i + cpi[s1] * p1r;
        }
      });
    }
  });

  // ---- readout: z_i = sum |A|^2 * (1 - 2*parity(m & vz_i)); norm = sum|A|^2
  float n2 = 0.0f, z0 = 0.0f, z1 = 0.0f;
  {
    const bool b0l = (__builtin_popcount(lane & (int)(MT.vz0 & 63u)) & 1) != 0;
    const bool b1l = (__builtin_popcount(lane & (int)(MT.vz1 & 63u)) & 1) != 0;
    static_for<0, 16>([&](auto R_) {
      constexpr int r = decltype(R_)::value;
      constexpr int s0 = __builtin_popcount(r & (int)((MT.vz0 >> 6) & 15u)) & 1;
      constexpr int s1 = __builtin_popcount(r & (int)((MT.vz1 >> 6) & 15u)) & 1;
      float wgt = are[r] * are[r] + aim[r] * aim[r];
      n2 += wgt;
      z0 += (b0l != (s0 != 0)) ? -wgt : wgt;
      z1 += (b1l != (s1 != 0)) ? -wgt : wgt;
    });
  }

  // wave-wide butterfly reduce
#pragma unroll
  for (int off = 1; off < 64; off <<= 1) {
    n2 += __shfl_xor(n2, off);
    z0 += __shfl_xor(z0, off);
    z1 += __shfl_xor(z1, off);
  }

  if (lane == 0) {
    const float inv = 1.0f / n2;
    const float l0 = z0 * inv, l1 = z1 * inv;
    const float m = fmaxf(l0, l1);
    const float lse = m + logf(expf(l0 - m) + expf(l1 - m));
    const int yy = y[sample];
    const float ly = (yy == 0) ? l0 : l1;
    losses[sample] = lse - ly;
  }
}

// ---------------------------------------------------------------------------
__global__ __launch_bounds__(256) void reduce_mean(const float* __restrict__ losses,
                                                   float* __restrict__ out) {
  __shared__ float sm[256];
  float acc = 0.0f;
  for (int i = threadIdx.x; i < BATCH; i += 256) acc += losses[i];
  sm[threadIdx.x] = acc;
  __syncthreads();
  for (int s = 128; s > 0; s >>= 1) {
    if (threadIdx.x < s) sm[threadIdx.x] += sm[threadIdx.x + s];
    __syncthreads();
  }
  if (threadIdx.x == 0) out[0] = sm[0] * (1.0f / (float)BATCH);
}

// ---------------------------------------------------------------------------
extern "C" void kernel_launch(void* const* d_in, const int* in_sizes, int n_in,
                              void* d_out, int out_size, void* d_ws, size_t ws_size,
                              hipStream_t stream) {
  const float* x = (const float*)d_in[0];   // [16384, 784] f32
  const float* w = (const float*)d_in[1];   // [5, 10, 3] f32
  const int*   y = (const int*)d_in[2];     // [16384] i32
  float* losses = (float*)d_ws;             // 16384 f32 scratch

  qcl_sim<<<BATCH / 4, 256, 0, stream>>>(x, w, y, losses);
  reduce_mean<<<1, 256, 0, stream>>>(losses, (float*)d_out);
}

// Round 2
// 281.088 us; speedup vs baseline: 1.0147x; 1.0147x over previous
//
#include <hip/hip_runtime.h>
#include <type_traits>
#include <utility>

#define NQ 10
#define N_DEPTH 5
#define DIM 1024
#define BATCH 16384
#define IN_DIM 784
#define NGATES 50

typedef float f32x2 __attribute__((ext_vector_type(2)));
typedef float f32x4 __attribute__((ext_vector_type(4)));

// ---------------------------------------------------------------------------
// Compile-time mask tables: CNOTs absorbed into GF(2)-linear index transform.
// bit i of logical index = parity(m & v[i]); flipping logical bit i: m ^= p[i].
// CNOT(c,t): v[t] ^= v[c]; p[c] ^= p[t].
// ---------------------------------------------------------------------------
struct MaskTab {
  unsigned v[NGATES];
  unsigned p[NGATES];
  unsigned vz0, vz1;
};

constexpr MaskTab make_masks() {
  MaskTab t{};
  unsigned v[NQ], p[NQ];
  for (int i = 0; i < NQ; ++i) { v[i] = 1u << (9 - i); p[i] = 1u << (9 - i); }
  for (int d = 0; d < N_DEPTH; ++d) {
    for (int i = 0; i < NQ; ++i) {      // CNOT ring: control i, target (i+1)%NQ
      int c = i, tt = (i + 1) % NQ;
      v[tt] ^= v[c];
      p[c]  ^= p[tt];
    }
    for (int i = 0; i < NQ; ++i) {
      t.v[d * NQ + i] = v[i];
      t.p[d * NQ + i] = p[i];
    }
  }
  t.vz0 = v[0];
  t.vz1 = v[1];
  return t;
}

constexpr MaskTab MT = make_masks();

template <int I, int N, typename F>
__device__ __forceinline__ void static_for(F&& f) {
  if constexpr (I < N) {
    f(std::integral_constant<int, I>{});
    static_for<I + 1, N>(static_cast<F&&>(f));
  }
}

// ---------------------------------------------------------------------------
// Packed-f32 complex arithmetic (VOP3P). d = c*v (complex), a += c*v.
// lane-local: (re,im) in a 64-bit VGPR pair.
// ---------------------------------------------------------------------------
__device__ __forceinline__ f32x2 cmul(f32x2 c, f32x2 v) {
  f32x2 d;
  asm("v_pk_mul_f32 %0, %1, %2 op_sel:[0,0] op_sel_hi:[0,1]\n\t"
      "v_pk_fma_f32 %0, %1, %2, %0 op_sel:[1,1,0] op_sel_hi:[1,0,1] neg_lo:[1,0,0]"
      : "=&v"(d) : "v"(c), "v"(v));
  return d;
}

__device__ __forceinline__ f32x2 cfma(f32x2 a, f32x2 c, f32x2 v) {
  asm("v_pk_fma_f32 %0, %1, %2, %0 op_sel:[0,0,0] op_sel_hi:[0,1,1]\n\t"
      "v_pk_fma_f32 %0, %1, %2, %0 op_sel:[1,1,0] op_sel_hi:[1,0,1] neg_lo:[1,0,0]"
      : "+v"(a) : "v"(c), "v"(v));
  return a;
}

// ---------------------------------------------------------------------------
// One wave = one sample. 1024 complex amps = 16 float2 per lane,
// index m = (r << 6) | lane.
// ---------------------------------------------------------------------------
__global__ __launch_bounds__(256) void qcl_sim(const float* __restrict__ x,
                                               const float* __restrict__ w,
                                               const int* __restrict__ y,
                                               float* __restrict__ partial) {
  __shared__ f32x4 UL4[NGATES][2];
  __shared__ float blksum[4];

  const int tid = threadIdx.x;
  if (tid < NGATES) {
    // qml.Rot(phi, theta, omega) = RZ(omega) RY(theta) RZ(phi)
    float phi = w[tid * 3 + 0], th = w[tid * 3 + 1], om = w[tid * 3 + 2];
    float ct = cosf(th * 0.5f), st = sinf(th * 0.5f);
    float aa = (phi + om) * 0.5f, bb = (phi - om) * 0.5f;
    float cA = cosf(aa), sA = sinf(aa), cB = cosf(bb), sB = sinf(bb);
    UL4[tid][0] = f32x4{ ct * cA, -ct * sA,    // m00 = e^{-ia} c
                         -st * cB, -st * sB }; // m01 = -e^{+ib} s
    UL4[tid][1] = f32x4{ st * cB, -st * sB,    // m10 = e^{-ib} s
                         ct * cA,  ct * sA };  // m11 = e^{+ia} c
  }
  __syncthreads();

  const int wave = tid >> 6;
  const int lane = tid & 63;
  const int sample = blockIdx.x * 4 + wave;

  // ---- amplitude embedding (unnormalized; norm folded into readout) ----
  const float* xr = x + (size_t)sample * IN_DIM;
  f32x2 a[16];
#pragma unroll
  for (int r = 0; r < 16; ++r) a[r] = f32x2{0.0f, 0.0f};
#pragma unroll
  for (int r = 0; r < 12; ++r) a[r].x = xr[r * 64 + lane];   // 768 coalesced
  if (lane < 16) a[12].x = xr[768 + lane];                   // tail 16

  // ---- 50 Rot gates on generalized qubits (CNOTs folded into masks) ----
  static_for<0, NGATES>([&](auto G_) {
    constexpr int G = decltype(G_)::value;
    constexpr unsigned v = MT.v[G];
    constexpr unsigned p = MT.p[G];
    constexpr unsigned vl = v & 63u, vr = (v >> 6) & 15u;
    constexpr unsigned pl = p & 63u, pr = (p >> 6) & 15u;

    const f32x4 A = UL4[G][0];
    const f32x4 B = UL4[G][1];
    const f32x2 u00 = {A.x, A.y}, u01 = {A.z, A.w};
    const f32x2 u10 = {B.x, B.y}, u11 = {B.z, B.w};

    const bool bl = (__builtin_popcount(lane & (int)vl) & 1) != 0;
    // effective bit b = bl ^ s (s = static per-register parity):
    // new = U[b][b]*own + U[b][!b]*partner
    f32x2 co[2], cp[2];
    co[0].x = bl ? u11.x : u00.x;  co[0].y = bl ? u11.y : u00.y;
    cp[0].x = bl ? u10.x : u01.x;  cp[0].y = bl ? u10.y : u01.y;
    co[1].x = bl ? u00.x : u11.x;  co[1].y = bl ? u00.y : u11.y;
    cp[1].x = bl ? u01.x : u10.x;  cp[1].y = bl ? u01.y : u10.y;

    if constexpr (pr == 0) {
      // partner in same register, different lane
      static_for<0, 16>([&](auto R_) {
        constexpr int r = decltype(R_)::value;
        constexpr int s = __builtin_popcount(r & (int)vr) & 1;
        f32x2 o = a[r], q;
        q.x = __shfl_xor(o.x, (int)pl);
        q.y = __shfl_xor(o.y, (int)pl);
        a[r] = cfma(cmul(co[s], o), cp[s], q);
      });
    } else {
      // partner in register r^pr (and lane^pl if pl!=0); process pairs once
      static_for<0, 16>([&](auto R_) {
        constexpr int r = decltype(R_)::value;
        constexpr int r2 = r ^ (int)pr;
        if constexpr (r < r2) {
          constexpr int s0 = __builtin_popcount(r & (int)vr) & 1;
          constexpr int s1 = __builtin_popcount(r2 & (int)vr) & 1;
          f32x2 o0 = a[r], o1 = a[r2];
          f32x2 q0, q1;
          if constexpr (pl != 0) {
            q0.x = __shfl_xor(o1.x, (int)pl); q0.y = __shfl_xor(o1.y, (int)pl);
            q1.x = __shfl_xor(o0.x, (int)pl); q1.y = __shfl_xor(o0.y, (int)pl);
          } else {
            q0 = o1; q1 = o0;
          }
          a[r]  = cfma(cmul(co[s0], o0), cp[s0], q0);
          a[r2] = cfma(cmul(co[s1], o1), cp[s1], q1);
        }
      });
    }
  });

  // ---- readout: z_i = sum |A|^2 * (1 - 2*parity(m & vz_i)); n2 = sum|A|^2
  float n2 = 0.0f, z0 = 0.0f, z1 = 0.0f;
  {
    const bool b0l = (__builtin_popcount(lane & (int)(MT.vz0 & 63u)) & 1) != 0;
    const bool b1l = (__builtin_popcount(lane & (int)(MT.vz1 & 63u)) & 1) != 0;
    static_for<0, 16>([&](auto R_) {
      constexpr int r = decltype(R_)::value;
      constexpr int s0 = __builtin_popcount(r & (int)((MT.vz0 >> 6) & 15u)) & 1;
      constexpr int s1 = __builtin_popcount(r & (int)((MT.vz1 >> 6) & 15u)) & 1;
      float wgt = a[r].x * a[r].x + a[r].y * a[r].y;
      n2 += wgt;
      z0 += (b0l != (s0 != 0)) ? -wgt : wgt;
      z1 += (b1l != (s1 != 0)) ? -wgt : wgt;
    });
  }

#pragma unroll
  for (int off = 1; off < 64; off <<= 1) {
    n2 += __shfl_xor(n2, off);
    z0 += __shfl_xor(z0, off);
    z1 += __shfl_xor(z1, off);
  }

  if (lane == 0) {
    const float inv = 1.0f / n2;
    const float l0 = z0 * inv, l1 = z1 * inv;
    const float m = fmaxf(l0, l1);
    const float lse = m + logf(expf(l0 - m) + expf(l1 - m));
    const int yy = y[sample];
    const float ly = (yy == 0) ? l0 : l1;
    blksum[wave] = lse - ly;
  }
  __syncthreads();
  if (tid == 0)
    partial[blockIdx.x] = blksum[0] + blksum[1] + blksum[2] + blksum[3];
}

// ---------------------------------------------------------------------------
__global__ __launch_bounds__(256) void reduce_mean(const float* __restrict__ partial,
                                                   float* __restrict__ out) {
  __shared__ float sm[256];
  float acc = 0.0f;
  for (int i = threadIdx.x; i < BATCH / 4; i += 256) acc += partial[i];
  sm[threadIdx.x] = acc;
  __syncthreads();
  for (int s = 128; s > 0; s >>= 1) {
    if (threadIdx.x < s) sm[threadIdx.x] += sm[threadIdx.x + s];
    __syncthreads();
  }
  if (threadIdx.x == 0) out[0] = sm[0] * (1.0f / (float)BATCH);
}

// ---------------------------------------------------------------------------
extern "C" void kernel_launch(void* const* d_in, const int* in_sizes, int n_in,
                              void* d_out, int out_size, void* d_ws, size_t ws_size,
                              hipStream_t stream) {
  const float* x = (const float*)d_in[0];   // [16384, 784] f32
  const float* w = (const float*)d_in[1];   // [5, 10, 3] f32
  const int*   y = (const int*)d_in[2];     // [16384] i32
  float* partial = (float*)d_ws;            // 4096 f32 scratch

  qcl_sim<<<BATCH / 4, 256, 0, stream>>>(x, w, y, partial);
  reduce_mean<<<1, 256, 0, stream>>>(partial, (float*)d_out);
}

// Round 3
// 241.487 us; speedup vs baseline: 1.1811x; 1.1640x over previous
//
#include <hip/hip_runtime.h>
#include <type_traits>
#include <utility>

#define NQ 10
#define N_DEPTH 5
#define DIM 1024
#define BATCH 16384
#define IN_DIM 784
#define NGATES 50

typedef float f32x2 __attribute__((ext_vector_type(2)));
typedef float f32x4 __attribute__((ext_vector_type(4)));

// ---------------------------------------------------------------------------
// Compile-time mask tables: CNOTs absorbed into GF(2)-linear index transform.
// bit i of logical index = parity(m & v[i]); flipping logical bit i: m ^= p[i].
// CNOT(c,t): v[t] ^= v[c]; p[c] ^= p[t].
// ---------------------------------------------------------------------------
struct MaskTab {
  unsigned v[NGATES];
  unsigned p[NGATES];
  unsigned vz0, vz1;
};

constexpr MaskTab make_masks() {
  MaskTab t{};
  unsigned v[NQ], p[NQ];
  for (int i = 0; i < NQ; ++i) { v[i] = 1u << (9 - i); p[i] = 1u << (9 - i); }
  for (int d = 0; d < N_DEPTH; ++d) {
    for (int i = 0; i < NQ; ++i) {      // CNOT ring: control i, target (i+1)%NQ
      int c = i, tt = (i + 1) % NQ;
      v[tt] ^= v[c];
      p[c]  ^= p[tt];
    }
    for (int i = 0; i < NQ; ++i) {
      t.v[d * NQ + i] = v[i];
      t.p[d * NQ + i] = p[i];
    }
  }
  t.vz0 = v[0];
  t.vz1 = v[1];
  return t;
}

constexpr MaskTab MT = make_masks();

template <int I, int N, typename F>
__device__ __forceinline__ void static_for(F&& f) {
  if constexpr (I < N) {
    f(std::integral_constant<int, I>{});
    static_for<I + 1, N>(static_cast<F&&>(f));
  }
}

// ---------------------------------------------------------------------------
// Cross-lane XOR exchange on the VALU (DPP + permlane), DS fallback for the
// expensive masks. VALU op cost per 32-bit word:
//   quad_perm(1,2,3)=1  half_mirror(7)=1  row_ror8(8)=1  row_mirror(15)=1
//   composites of those = 2; +3 for bit4 (permlane16_swap + add/sub)
//   and +3 for bit5 (permlane32_swap + add/sub).
// ---------------------------------------------------------------------------
constexpr int xcost(unsigned m) {
  constexpr int t[16] = {0,1,1,1,2,2,2,1,1,2,2,2,2,2,2,1};
  return t[m & 15u] + (((m >> 4) & 1u) ? 3 : 0) + (((m >> 5) & 1u) ? 3 : 0);
}

template <int CTRL>
__device__ __forceinline__ float dppf(float x) {
  int xi = (int)__float_as_uint(x);
  return __uint_as_float(
      (unsigned)__builtin_amdgcn_update_dpp(xi, xi, CTRL, 0xF, 0xF, false));
}

// Self-swap via permlane{16,32}_swap: the two outputs at lane l hold, as a
// set, {x[l], x[l^K]}; (a+b)-x recovers the partner independent of operand
// ordering semantics. Error <= 1 ulp of the larger magnitude.
__device__ __forceinline__ float plswap16(float x) {
  float a = x, b = x;
  asm("s_nop 1\n\t"
      "v_permlane16_swap_b32 %0, %1" : "+v"(a), "+v"(b));
  return (a + b) - x;
}
__device__ __forceinline__ float plswap32(float x) {
  float a = x, b = x;
  asm("s_nop 1\n\t"
      "v_permlane32_swap_b32 %0, %1" : "+v"(a), "+v"(b));
  return (a + b) - x;
}

template <unsigned M>
__device__ __forceinline__ float xlane_f(float x) {
  float r = x;
  constexpr unsigned m4 = M & 15u;
  if constexpr (m4 == 1u)  r = dppf<0x0B1>(r);                       // quad xor1
  else if constexpr (m4 == 2u)  r = dppf<0x04E>(r);                  // quad xor2
  else if constexpr (m4 == 3u)  r = dppf<0x01B>(r);                  // quad xor3
  else if constexpr (m4 == 4u)  { r = dppf<0x141>(r); r = dppf<0x01B>(r); }
  else if constexpr (m4 == 5u)  { r = dppf<0x141>(r); r = dppf<0x04E>(r); }
  else if constexpr (m4 == 6u)  { r = dppf<0x141>(r); r = dppf<0x0B1>(r); }
  else if constexpr (m4 == 7u)  r = dppf<0x141>(r);                  // half_mirror
  else if constexpr (m4 == 8u)  r = dppf<0x128>(r);                  // row_ror:8
  else if constexpr (m4 == 9u)  { r = dppf<0x128>(r); r = dppf<0x0B1>(r); }
  else if constexpr (m4 == 10u) { r = dppf<0x128>(r); r = dppf<0x04E>(r); }
  else if constexpr (m4 == 11u) { r = dppf<0x128>(r); r = dppf<0x01B>(r); }
  else if constexpr (m4 == 12u) { r = dppf<0x140>(r); r = dppf<0x01B>(r); }
  else if constexpr (m4 == 13u) { r = dppf<0x140>(r); r = dppf<0x04E>(r); }
  else if constexpr (m4 == 14u) { r = dppf<0x140>(r); r = dppf<0x0B1>(r); }
  else if constexpr (m4 == 15u) r = dppf<0x140>(r);                  // row_mirror
  if constexpr ((M & 16u) != 0u) r = plswap16(r);
  if constexpr ((M & 32u) != 0u) r = plswap32(r);
  return r;
}

template <unsigned M>
__device__ __forceinline__ f32x2 xchg(f32x2 v) {
  if constexpr (M == 0u) {
    return v;
  } else if constexpr (xcost(M) >= 5) {
    f32x2 r;
    r.x = __shfl_xor(v.x, (int)M);
    r.y = __shfl_xor(v.y, (int)M);
    return r;
  } else {
    f32x2 r;
    r.x = xlane_f<M>(v.x);
    r.y = xlane_f<M>(v.y);
    return r;
  }
}

// ---------------------------------------------------------------------------
// d = co*o + cp*q (complex), all packed (re,im) in 64-bit VGPR pairs.
// One asm block of 4 VOP3P instructions (patterns verified in round 1).
// ---------------------------------------------------------------------------
__device__ __forceinline__ f32x2 ampfma(f32x2 o, f32x2 q, f32x2 co, f32x2 cp) {
  f32x2 d;
  asm("v_pk_mul_f32 %0, %2, %1 op_sel:[0,0] op_sel_hi:[0,1]\n\t"
      "v_pk_fma_f32 %0, %2, %1, %0 op_sel:[1,1,0] op_sel_hi:[1,0,1] neg_lo:[1,0,0]\n\t"
      "v_pk_fma_f32 %0, %3, %4, %0 op_sel:[0,0,0] op_sel_hi:[0,1,1]\n\t"
      "v_pk_fma_f32 %0, %3, %4, %0 op_sel:[1,1,0] op_sel_hi:[1,0,1] neg_lo:[1,0,0]"
      : "=&v"(d)
      : "v"(o), "v"(co), "v"(cp), "v"(q));
  return d;
}

__device__ __forceinline__ float fxor(float x, unsigned m) {
  return __uint_as_float(__float_as_uint(x) ^ m);
}

// ---------------------------------------------------------------------------
// One wave = one sample. 1024 complex amps = 16 float2 per lane,
// index m = (r << 6) | lane.
// ---------------------------------------------------------------------------
__global__ __launch_bounds__(256) void qcl_sim(const float* __restrict__ x,
                                               const float* __restrict__ w,
                                               const int* __restrict__ y,
                                               float* __restrict__ partial) {
  __shared__ f32x4 UL4[NGATES];
  __shared__ float blksum[4];

  const int tid = threadIdx.x;
  if (tid < NGATES) {
    // qml.Rot(phi, theta, omega) = RZ(omega) RY(theta) RZ(phi)
    float phi = w[tid * 3 + 0], th = w[tid * 3 + 1], om = w[tid * 3 + 2];
    float ct = cosf(th * 0.5f), st = sinf(th * 0.5f);
    float aa = (phi + om) * 0.5f, bb = (phi - om) * 0.5f;
    float cA = cosf(aa), sA = sinf(aa), cB = cosf(bb), sB = sinf(bb);
    // u00 = e^{-ia} c ; u01 = -e^{+ib} s   (u11 = conj(u00), u10 = -conj(u01))
    UL4[tid] = f32x4{ ct * cA, -ct * sA, -st * cB, -st * sB };
  }
  __syncthreads();

  const int wave = tid >> 6;
  const int lane = tid & 63;
  const int sample = blockIdx.x * 4 + wave;

  // ---- amplitude embedding (unnormalized; norm folded into readout) ----
  const float* xr = x + (size_t)sample * IN_DIM;
  f32x2 a[16];
#pragma unroll
  for (int r = 0; r < 16; ++r) a[r] = f32x2{0.0f, 0.0f};
#pragma unroll
  for (int r = 0; r < 12; ++r) a[r].x = xr[r * 64 + lane];   // 768 coalesced
  if (lane < 16) a[12].x = xr[768 + lane];                   // tail 16

  // ---- 50 Rot gates on generalized qubits (CNOTs folded into masks) ----
  static_for<0, NGATES>([&](auto G_) {
    constexpr int G = decltype(G_)::value;
    constexpr unsigned v = MT.v[G];
    constexpr unsigned p = MT.p[G];
    constexpr unsigned vl = v & 63u, vr = (v >> 6) & 15u;
    constexpr unsigned pl = p & 63u, pr = (p >> 6) & 15u;

    const f32x4 A = UL4[G];
    const f32x2 u00 = {A.x, A.y}, u01 = {A.z, A.w};

    // effective bit b = bl ^ s; coefficients via conjugate-sign structure:
    //   co(b) = b ? conj(u00) : u00      -> xor sign of imag
    //   cp(b) = b ? -conj(u01) : u01     -> xor sign of real
    const unsigned sg = (unsigned)(__builtin_popcount((int)(lane & vl)) & 1) << 31;
    const f32x2 co0 = {u00.x, fxor(u00.y, sg)};
    const f32x2 cp0 = {fxor(u01.x, sg), u01.y};
    const f32x2 co1 = {u00.x, fxor(u00.y, sg ^ 0x80000000u)};
    const f32x2 cp1 = {fxor(u01.x, sg ^ 0x80000000u), u01.y};

    if constexpr (pr == 0) {
      // partner in same register, different lane
      static_for<0, 16>([&](auto R_) {
        constexpr int r = decltype(R_)::value;
        constexpr int s = __builtin_popcount(r & (int)vr) & 1;
        f32x2 o = a[r];
        f32x2 q = xchg<pl>(o);
        a[r] = ampfma(o, q, s ? co1 : co0, s ? cp1 : cp0);
      });
    } else {
      // partner in register r^pr (and lane^pl if pl!=0); process pairs once
      static_for<0, 16>([&](auto R_) {
        constexpr int r = decltype(R_)::value;
        constexpr int r2 = r ^ (int)pr;
        if constexpr (r < r2) {
          constexpr int s0 = __builtin_popcount(r & (int)vr) & 1;
          constexpr int s1 = __builtin_popcount(r2 & (int)vr) & 1;
          f32x2 o0 = a[r], o1 = a[r2];
          f32x2 q0 = xchg<pl>(o1);
          f32x2 q1 = xchg<pl>(o0);
          a[r]  = ampfma(o0, q0, s0 ? co1 : co0, s0 ? cp1 : cp0);
          a[r2] = ampfma(o1, q1, s1 ? co1 : co0, s1 ? cp1 : cp0);
        }
      });
    }
  });

  // ---- readout: z_i = sum |A|^2 * (1 - 2*parity(m & vz_i)); n2 = sum|A|^2
  float n2 = 0.0f, z0 = 0.0f, z1 = 0.0f;
  {
    const bool b0l = (__builtin_popcount((int)(lane & (MT.vz0 & 63u))) & 1) != 0;
    const bool b1l = (__builtin_popcount((int)(lane & (MT.vz1 & 63u))) & 1) != 0;
    static_for<0, 16>([&](auto R_) {
      constexpr int r = decltype(R_)::value;
      constexpr int s0 = __builtin_popcount(r & (int)((MT.vz0 >> 6) & 15u)) & 1;
      constexpr int s1 = __builtin_popcount(r & (int)((MT.vz1 >> 6) & 15u)) & 1;
      float wgt = a[r].x * a[r].x + a[r].y * a[r].y;
      n2 += wgt;
      z0 += (b0l != (s0 != 0)) ? -wgt : wgt;
      z1 += (b1l != (s1 != 0)) ? -wgt : wgt;
    });
  }

#pragma unroll
  for (int off = 1; off < 64; off <<= 1) {
    n2 += __shfl_xor(n2, off);
    z0 += __shfl_xor(z0, off);
    z1 += __shfl_xor(z1, off);
  }

  if (lane == 0) {
    const float inv = 1.0f / n2;
    const float l0 = z0 * inv, l1 = z1 * inv;
    const float m = fmaxf(l0, l1);
    const float lse = m + logf(expf(l0 - m) + expf(l1 - m));
    const int yy = y[sample];
    const float ly = (yy == 0) ? l0 : l1;
    blksum[wave] = lse - ly;
  }
  __syncthreads();
  if (tid == 0)
    partial[blockIdx.x] = blksum[0] + blksum[1] + blksum[2] + blksum[3];
}

// ---------------------------------------------------------------------------
__global__ __launch_bounds__(256) void reduce_mean(const float* __restrict__ partial,
                                                   float* __restrict__ out) {
  __shared__ float sm[256];
  float acc = 0.0f;
  for (int i = threadIdx.x; i < BATCH / 4; i += 256) acc += partial[i];
  sm[threadIdx.x] = acc;
  __syncthreads();
  for (int s = 128; s > 0; s >>= 1) {
    if (threadIdx.x < s) sm[threadIdx.x] += sm[threadIdx.x + s];
    __syncthreads();
  }
  if (threadIdx.x == 0) out[0] = sm[0] * (1.0f / (float)BATCH);
}

// ---------------------------------------------------------------------------
extern "C" void kernel_launch(void* const* d_in, const int* in_sizes, int n_in,
                              void* d_out, int out_size, void* d_ws, size_t ws_size,
                              hipStream_t stream) {
  const float* x = (const float*)d_in[0];   // [16384, 784] f32
  const float* w = (const float*)d_in[1];   // [5, 10, 3] f32
  const int*   y = (const int*)d_in[2];     // [16384] i32
  float* partial = (float*)d_ws;            // 4096 f32 scratch

  qcl_sim<<<BATCH / 4, 256, 0, stream>>>(x, w, y, partial);
  reduce_mean<<<1, 256, 0, stream>>>(partial, (float*)d_out);
}

// Round 4
// 184.015 us; speedup vs baseline: 1.5499x; 1.3123x over previous
//
#include <hip/hip_runtime.h>
#include <type_traits>

#define NQ 10
#define N_DEPTH 5
#define DIM 1024
#define BATCH 16384
#define IN_DIM 784
#define NGATES 50
#define KPAD 800      // GEMM K extent (25*32)
#define KALLOC 832    // W2 rows allocated (13*64 transpose tiles)
#define NOUT 2048     // 2*DIM interleaved (re,im) columns

typedef float f32x2 __attribute__((ext_vector_type(2)));
typedef float f32x4 __attribute__((ext_vector_type(4)));
typedef short bf16x8 __attribute__((ext_vector_type(8)));
typedef unsigned u32x4 __attribute__((ext_vector_type(4)));

// ---------------------------------------------------------------------------
// Compile-time mask tables: CNOTs absorbed into GF(2)-linear index transform.
// ---------------------------------------------------------------------------
struct MaskTab {
  unsigned v[NGATES];
  unsigned p[NGATES];
  unsigned vz0, vz1;
};

constexpr MaskTab make_masks() {
  MaskTab t{};
  unsigned v[NQ], p[NQ];
  for (int i = 0; i < NQ; ++i) { v[i] = 1u << (9 - i); p[i] = 1u << (9 - i); }
  for (int d = 0; d < N_DEPTH; ++d) {
    for (int i = 0; i < NQ; ++i) {
      int c = i, tt = (i + 1) % NQ;
      v[tt] ^= v[c];
      p[c]  ^= p[tt];
    }
    for (int i = 0; i < NQ; ++i) {
      t.v[d * NQ + i] = v[i];
      t.p[d * NQ + i] = p[i];
    }
  }
  t.vz0 = v[0];
  t.vz1 = v[1];
  return t;
}

constexpr MaskTab MT = make_masks();

template <int I, int N, typename F>
__device__ __forceinline__ void static_for(F&& f) {
  if constexpr (I < N) {
    f(std::integral_constant<int, I>{});
    static_for<I + 1, N>(static_cast<F&&>(f));
  }
}

// ---------------------------------------------------------------------------
// Cross-lane XOR exchange (VALU DPP/permlane; DS fallback) — verified r2/r3.
// ---------------------------------------------------------------------------
constexpr int xcost(unsigned m) {
  constexpr int t[16] = {0,1,1,1,2,2,2,1,1,2,2,2,2,2,2,1};
  return t[m & 15u] + (((m >> 4) & 1u) ? 3 : 0) + (((m >> 5) & 1u) ? 3 : 0);
}

template <int CTRL>
__device__ __forceinline__ float dppf(float x) {
  int xi = (int)__float_as_uint(x);
  return __uint_as_float(
      (unsigned)__builtin_amdgcn_update_dpp(xi, xi, CTRL, 0xF, 0xF, false));
}

__device__ __forceinline__ float plswap16(float x) {
  float a = x, b = x;
  asm("s_nop 1\n\t"
      "v_permlane16_swap_b32 %0, %1" : "+v"(a), "+v"(b));
  return (a + b) - x;
}
__device__ __forceinline__ float plswap32(float x) {
  float a = x, b = x;
  asm("s_nop 1\n\t"
      "v_permlane32_swap_b32 %0, %1" : "+v"(a), "+v"(b));
  return (a + b) - x;
}

template <unsigned M>
__device__ __forceinline__ float xlane_f(float x) {
  float r = x;
  constexpr unsigned m4 = M & 15u;
  if constexpr (m4 == 1u)  r = dppf<0x0B1>(r);
  else if constexpr (m4 == 2u)  r = dppf<0x04E>(r);
  else if constexpr (m4 == 3u)  r = dppf<0x01B>(r);
  else if constexpr (m4 == 4u)  { r = dppf<0x141>(r); r = dppf<0x01B>(r); }
  else if constexpr (m4 == 5u)  { r = dppf<0x141>(r); r = dppf<0x04E>(r); }
  else if constexpr (m4 == 6u)  { r = dppf<0x141>(r); r = dppf<0x0B1>(r); }
  else if constexpr (m4 == 7u)  r = dppf<0x141>(r);
  else if constexpr (m4 == 8u)  r = dppf<0x128>(r);
  else if constexpr (m4 == 9u)  { r = dppf<0x128>(r); r = dppf<0x0B1>(r); }
  else if constexpr (m4 == 10u) { r = dppf<0x128>(r); r = dppf<0x04E>(r); }
  else if constexpr (m4 == 11u) { r = dppf<0x128>(r); r = dppf<0x01B>(r); }
  else if constexpr (m4 == 12u) { r = dppf<0x140>(r); r = dppf<0x01B>(r); }
  else if constexpr (m4 == 13u) { r = dppf<0x140>(r); r = dppf<0x04E>(r); }
  else if constexpr (m4 == 14u) { r = dppf<0x140>(r); r = dppf<0x0B1>(r); }
  else if constexpr (m4 == 15u) r = dppf<0x140>(r);
  if constexpr ((M & 16u) != 0u) r = plswap16(r);
  if constexpr ((M & 32u) != 0u) r = plswap32(r);
  return r;
}

template <unsigned M>
__device__ __forceinline__ f32x2 xchg(f32x2 v) {
  if constexpr (M == 0u) {
    return v;
  } else if constexpr (xcost(M) >= 5) {
    f32x2 r;
    r.x = __shfl_xor(v.x, (int)M);
    r.y = __shfl_xor(v.y, (int)M);
    return r;
  } else {
    f32x2 r;
    r.x = xlane_f<M>(v.x);
    r.y = xlane_f<M>(v.y);
    return r;
  }
}

__device__ __forceinline__ f32x2 ampfma(f32x2 o, f32x2 q, f32x2 co, f32x2 cp) {
  f32x2 d;
  asm("v_pk_mul_f32 %0, %2, %1 op_sel:[0,0] op_sel_hi:[0,1]\n\t"
      "v_pk_fma_f32 %0, %2, %1, %0 op_sel:[1,1,0] op_sel_hi:[1,0,1] neg_lo:[1,0,0]\n\t"
      "v_pk_fma_f32 %0, %3, %4, %0 op_sel:[0,0,0] op_sel_hi:[0,1,1]\n\t"
      "v_pk_fma_f32 %0, %3, %4, %0 op_sel:[1,1,0] op_sel_hi:[1,0,1] neg_lo:[1,0,0]"
      : "=&v"(d)
      : "v"(o), "v"(co), "v"(cp), "v"(q));
  return d;
}

__device__ __forceinline__ float fxor(float x, unsigned m) {
  return __uint_as_float(__float_as_uint(x) ^ m);
}

__device__ __forceinline__ unsigned bf16pack(float lo, float hi) {
  unsigned a = __float_as_uint(lo), b = __float_as_uint(hi);
  unsigned ra = (a + 0x7fffu + ((a >> 16) & 1u)) >> 16;   // RNE
  unsigned rb = (b + 0x7fffu + ((b >> 16) & 1u)) >> 16;
  return (ra & 0xffffu) | (rb << 16);
}

// ---------------------------------------------------------------------------
// K1: simulate basis states e_j -> W2[j][2m+c] bf16 (rows j>=784 zeroed).
// One wave per j. Gate code identical to the verified r3 kernel.
// ---------------------------------------------------------------------------
__global__ __launch_bounds__(256) void build_w(const float* __restrict__ w,
                                               unsigned* __restrict__ W2u) {
  __shared__ f32x4 UL4[NGATES];
  const int tid = threadIdx.x;
  if (tid < NGATES) {
    float phi = w[tid * 3 + 0], th = w[tid * 3 + 1], om = w[tid * 3 + 2];
    float ct = cosf(th * 0.5f), st = sinf(th * 0.5f);
    float aa = (phi + om) * 0.5f, bb = (phi - om) * 0.5f;
    float cA = cosf(aa), sA = sinf(aa), cB = cosf(bb), sB = sinf(bb);
    UL4[tid] = f32x4{ ct * cA, -ct * sA, -st * cB, -st * sB };
  }
  __syncthreads();

  const int wave = tid >> 6, lane = tid & 63;
  const int j = blockIdx.x * 4 + wave;          // 0..831
  unsigned* rowp = W2u + (size_t)j * 1024;      // 1024 u32 = 2048 bf16

  if (j >= IN_DIM) {                            // zero pad rows
    static_for<0, 16>([&](auto R_) { rowp[decltype(R_)::value * 64 + lane] = 0u; });
    return;
  }

  f32x2 a[16];
  static_for<0, 16>([&](auto R_) {
    constexpr int r = decltype(R_)::value;
    a[r] = f32x2{0.0f, 0.0f};
    if (r == (j >> 6) && lane == (j & 63)) a[r].x = 1.0f;
  });

  static_for<0, NGATES>([&](auto G_) {
    constexpr int G = decltype(G_)::value;
    constexpr unsigned v = MT.v[G];
    constexpr unsigned p = MT.p[G];
    constexpr unsigned vl = v & 63u, vr = (v >> 6) & 15u;
    constexpr unsigned pl = p & 63u, pr = (p >> 6) & 15u;

    const f32x4 A = UL4[G];
    const f32x2 u00 = {A.x, A.y}, u01 = {A.z, A.w};
    const unsigned sg = (unsigned)(__builtin_popcount((int)(lane & vl)) & 1) << 31;
    const f32x2 co0 = {u00.x, fxor(u00.y, sg)};
    const f32x2 cp0 = {fxor(u01.x, sg), u01.y};
    const f32x2 co1 = {u00.x, fxor(u00.y, sg ^ 0x80000000u)};
    const f32x2 cp1 = {fxor(u01.x, sg ^ 0x80000000u), u01.y};

    if constexpr (pr == 0) {
      static_for<0, 16>([&](auto R_) {
        constexpr int r = decltype(R_)::value;
        constexpr int s = __builtin_popcount(r & (int)vr) & 1;
        f32x2 o = a[r];
        f32x2 q = xchg<pl>(o);
        a[r] = ampfma(o, q, s ? co1 : co0, s ? cp1 : cp0);
      });
    } else {
      static_for<0, 16>([&](auto R_) {
        constexpr int r = decltype(R_)::value;
        constexpr int r2 = r ^ (int)pr;
        if constexpr (r < r2) {
          constexpr int s0 = __builtin_popcount(r & (int)vr) & 1;
          constexpr int s1 = __builtin_popcount(r2 & (int)vr) & 1;
          f32x2 o0 = a[r], o1 = a[r2];
          f32x2 q0 = xchg<pl>(o1);
          f32x2 q1 = xchg<pl>(o0);
          a[r]  = ampfma(o0, q0, s0 ? co1 : co0, s0 ? cp1 : cp0);
          a[r2] = ampfma(o1, q1, s1 ? co1 : co0, s1 ? cp1 : cp0);
        }
      });
    }
  });

  // store interleaved (re,im) bf16 pairs: u32 at column m = (r<<6)|lane
  static_for<0, 16>([&](auto R_) {
    constexpr int r = decltype(R_)::value;
    rowp[r * 64 + lane] = bf16pack(a[r].x, a[r].y);
  });
}

// ---------------------------------------------------------------------------
// K2: transpose W2 [832][2048] -> W2T [2048][832] (bf16), 64x64 tiles.
// ---------------------------------------------------------------------------
__global__ __launch_bounds__(256) void transpose_w(const unsigned* __restrict__ W2u,
                                                   unsigned* __restrict__ W2Tu) {
  __shared__ unsigned tile[64][33];
  const int j0 = blockIdx.x * 64;   // gridDim.x = 13
  const int n0 = blockIdx.y * 64;   // gridDim.y = 32
  const int t = threadIdx.x;
#pragma unroll
  for (int i = 0; i < 8; ++i) {
    const int idx = i * 256 + t;
    const int jr = idx >> 5, nc = idx & 31;
    tile[jr][nc] = W2u[(size_t)(j0 + jr) * 1024 + (n0 >> 1) + nc];
  }
  __syncthreads();
#pragma unroll
  for (int i = 0; i < 8; ++i) {
    const int idx = i * 256 + t;
    const int nr = idx >> 5, jc = idx & 31;
    const unsigned lo = tile[jc * 2][nr >> 1];
    const unsigned hi = tile[jc * 2 + 1][nr >> 1];
    const unsigned sh = (unsigned)(nr & 1) * 16u;
    const unsigned val = ((lo >> sh) & 0xffffu) | (((hi >> sh) & 0xffffu) << 16);
    W2Tu[(size_t)(n0 + nr) * (KALLOC / 2) + (j0 >> 1) + jc] = val;
  }
}

// ---------------------------------------------------------------------------
// K3: fused GEMM + readout. Out[s][n] = sum_j X[s][j] * W2T[n][j], epilogue
// reduces n2/z0/z1 per sample. 128x128 tile, BK=32, 4 waves (2x2), 4x4 frags
// of mfma_f32_16x16x32_bf16. XOR-swizzled LDS (byte ^= (row&7)<<4).
// ---------------------------------------------------------------------------
__global__ __launch_bounds__(256) void gemm_fused(const float* __restrict__ X,
                                                  const unsigned short* __restrict__ W2T,
                                                  float* __restrict__ accb) {
  __shared__ u32x4 A_l4[512];   // 8 KB: A tile [128 m][32 k] bf16, swizzled
  __shared__ u32x4 B_l4[512];   // 8 KB: B tile [128 n][32 k] bf16, swizzled
  char* A_l = (char*)A_l4;
  char* B_l = (char*)B_l4;

  const int tid = threadIdx.x;
  // XCD-chunked swizzle (2048 % 8 == 0 -> bijective), nb innermost so each
  // XCD keeps the full 3.4MB B matrix + few A slabs L2-resident.
  const int orig = blockIdx.x;
  const int bx = (orig & 7) * 256 + (orig >> 3);
  const int mb = bx >> 4, nb = bx & 15;
  const int m0 = mb * 128, n0 = nb * 128;

  const int lane = tid & 63, w = tid >> 6;
  const int wm = w >> 1, wn = w & 1;

  // frag read offsets (constant across K-steps): row-major [row][32k] 64B rows
  const int swz = (lane & 7) << 4;
  const int hi16 = (lane >> 4) << 4;
  int a_off[4], b_off[4];
#pragma unroll
  for (int f = 0; f < 4; ++f) {
    a_off[f] = (((wm * 64 + f * 16 + (lane & 15)) << 6) + hi16) ^ swz;
    b_off[f] = (((wn * 64 + f * 16 + (lane & 15)) << 6) + hi16) ^ swz;
  }

  f32x4 acc[4][4];
#pragma unroll
  for (int fm = 0; fm < 4; ++fm)
#pragma unroll
    for (int fn = 0; fn < 4; ++fn) acc[fm][fn] = f32x4{0, 0, 0, 0};

  for (int ks = 0; ks < 25; ++ks) {
    const int k0 = ks * 32;
#pragma unroll
    for (int h = 0; h < 2; ++h) {
      const int c = tid + h * 256;                  // chunk 0..511
      const int row = c >> 2, kc = (c & 3) * 8;
      const int phys = (c << 4) ^ (((c >> 2) & 7) << 4);
      // B: bf16 direct
      u32x4 bv = *(const u32x4*)(W2T + (size_t)(n0 + row) * KALLOC + k0 + kc);
      *(u32x4*)(B_l + phys) = bv;
      // A: f32 -> bf16 on the fly (zero-pad k >= 784)
      u32x4 av;
      if (k0 + kc < IN_DIM) {
        const float* src = X + (size_t)(m0 + row) * IN_DIM + k0 + kc;
        f32x4 v0 = *(const f32x4*)src;
        f32x4 v1 = *(const f32x4*)(src + 4);
        av = u32x4{bf16pack(v0.x, v0.y), bf16pack(v0.z, v0.w),
                   bf16pack(v1.x, v1.y), bf16pack(v1.z, v1.w)};
      } else {
        av = u32x4{0, 0, 0, 0};
      }
      *(u32x4*)(A_l + phys) = av;
    }
    __syncthreads();

    bf16x8 af[4], bfr[4];
#pragma unroll
    for (int f = 0; f < 4; ++f) {
      af[f]  = *(const bf16x8*)(A_l + a_off[f]);
      bfr[f] = *(const bf16x8*)(B_l + b_off[f]);
    }
#pragma unroll
    for (int fm = 0; fm < 4; ++fm)
#pragma unroll
      for (int fn = 0; fn < 4; ++fn)
        acc[fm][fn] = __builtin_amdgcn_mfma_f32_16x16x32_bf16(
            af[fm], bfr[fn], acc[fm][fn], 0, 0, 0);
    __syncthreads();
  }

  // ---- epilogue: per-sample (n2, z0, z1) partials for this n-block ----
  constexpr unsigned vz0 = MT.vz0, vz1 = MT.vz1;
  const int colbase = n0 + wn * 64 + (lane & 15);
#pragma unroll
  for (int fm = 0; fm < 4; ++fm) {
    float sn[4] = {0, 0, 0, 0}, s0[4] = {0, 0, 0, 0}, s1[4] = {0, 0, 0, 0};
#pragma unroll
    for (int fn = 0; fn < 4; ++fn) {
      const int st = (colbase + fn * 16) >> 1;     // quantum state index
      const float g0 = 1.0f - 2.0f * (float)(__popc(st & (int)vz0) & 1);
      const float g1 = 1.0f - 2.0f * (float)(__popc(st & (int)vz1) & 1);
#pragma unroll
      for (int r = 0; r < 4; ++r) {
        const float v = acc[fm][fn][r];
        const float wq = v * v;
        sn[r] += wq;
        s0[r] = fmaf(g0, wq, s0[r]);
        s1[r] = fmaf(g1, wq, s1[r]);
      }
    }
#pragma unroll
    for (int off = 1; off < 16; off <<= 1) {
#pragma unroll
      for (int r = 0; r < 4; ++r) {
        sn[r] += __shfl_xor(sn[r], off);
        s0[r] += __shfl_xor(s0[r], off);
        s1[r] += __shfl_xor(s1[r], off);
      }
    }
    if ((lane & 15) == 0) {
#pragma unroll
      for (int r = 0; r < 4; ++r) {
        const int m = m0 + wm * 64 + fm * 16 + (lane >> 4) * 4 + r;
        *(f32x4*)(accb + ((size_t)nb * BATCH + m) * 4) =
            f32x4{sn[r], s0[r], s1[r], 0.0f};
      }
    }
  }
}

// ---------------------------------------------------------------------------
// K4/K5: per-sample loss + mean reduction.
// ---------------------------------------------------------------------------
__global__ __launch_bounds__(256) void loss_partial(const float* __restrict__ accb,
                                                    const int* __restrict__ y,
                                                    float* __restrict__ partial) {
  const int s = blockIdx.x * 256 + threadIdx.x;
  float n2 = 0.0f, z0 = 0.0f, z1 = 0.0f;
#pragma unroll
  for (int nb = 0; nb < 16; ++nb) {
    f32x4 v = *(const f32x4*)(accb + ((size_t)nb * BATCH + s) * 4);
    n2 += v.x; z0 += v.y; z1 += v.z;
  }
  const float inv = 1.0f / n2;
  const float l0 = z0 * inv, l1 = z1 * inv;
  const float mx = fmaxf(l0, l1);
  const float lse = mx + logf(expf(l0 - mx) + expf(l1 - mx));
  float loss = lse - ((y[s] == 0) ? l0 : l1);

  __shared__ float sm[256];
  sm[threadIdx.x] = loss;
  __syncthreads();
  for (int st = 128; st > 0; st >>= 1) {
    if (threadIdx.x < st) sm[threadIdx.x] += sm[threadIdx.x + st];
    __syncthreads();
  }
  if (threadIdx.x == 0) partial[blockIdx.x] = sm[0];
}

__global__ __launch_bounds__(64) void loss_final(const float* __restrict__ partial,
                                                 float* __restrict__ out) {
  float v = partial[threadIdx.x];
#pragma unroll
  for (int off = 1; off < 64; off <<= 1) v += __shfl_xor(v, off);
  if (threadIdx.x == 0) out[0] = v * (1.0f / (float)BATCH);
}

// ---------------------------------------------------------------------------
extern "C" void kernel_launch(void* const* d_in, const int* in_sizes, int n_in,
                              void* d_out, int out_size, void* d_ws, size_t ws_size,
                              hipStream_t stream) {
  const float* x = (const float*)d_in[0];   // [16384, 784] f32
  const float* w = (const float*)d_in[1];   // [5, 10, 3] f32
  const int*   y = (const int*)d_in[2];     // [16384] i32

  char* ws = (char*)d_ws;
  unsigned* W2u  = (unsigned*)ws;                    // 832*1024 u32 = 3.41 MB
  unsigned* W2Tu = (unsigned*)(ws + 3407872);        // 2048*416 u32 = 3.41 MB
  float*    accb = (float*)(ws + 6815744);           // 16*16384*4 f32 = 4 MB
  float* partial = (float*)(ws + 11010048);          // 64 f32

  build_w<<<KALLOC / 4, 256, 0, stream>>>(w, W2u);
  transpose_w<<<dim3(13, 32), 256, 0, stream>>>(W2u, W2Tu);
  gemm_fused<<<2048, 256, 0, stream>>>(x, (const unsigned short*)W2Tu, accb);
  loss_partial<<<BATCH / 256, 256, 0, stream>>>(accb, y, partial);
  loss_final<<<1, 64, 0, stream>>>(partial, (float*)d_out);
}

// Round 5
// 148.189 us; speedup vs baseline: 1.9246x; 1.2418x over previous
//
#include <hip/hip_runtime.h>
#include <type_traits>

#define NQ 10
#define N_DEPTH 5
#define DIM 1024
#define BATCH 16384
#define IN_DIM 784
#define NGATES 50
#define KALLOC 832    // padded GEMM K extent (26*32); W2 rows >=784 are zero

typedef float f32x2 __attribute__((ext_vector_type(2)));
typedef float f32x4 __attribute__((ext_vector_type(4)));
typedef short bf16x8 __attribute__((ext_vector_type(8)));
typedef unsigned u32x4 __attribute__((ext_vector_type(4)));

// ---------------------------------------------------------------------------
// Compile-time mask tables: CNOTs absorbed into GF(2)-linear index transform.
// bit i of logical index = parity(m & v[i]); flip of logical bit i: m ^= p[i].
// ---------------------------------------------------------------------------
struct MaskTab {
  unsigned v[NGATES];
  unsigned p[NGATES];
  unsigned vz0, vz1;
};

constexpr MaskTab make_masks() {
  MaskTab t{};
  unsigned v[NQ], p[NQ];
  for (int i = 0; i < NQ; ++i) { v[i] = 1u << (9 - i); p[i] = 1u << (9 - i); }
  for (int d = 0; d < N_DEPTH; ++d) {
    for (int i = 0; i < NQ; ++i) {
      int c = i, tt = (i + 1) % NQ;
      v[tt] ^= v[c];
      p[c]  ^= p[tt];
    }
    for (int i = 0; i < NQ; ++i) {
      t.v[d * NQ + i] = v[i];
      t.p[d * NQ + i] = p[i];
    }
  }
  t.vz0 = v[0];
  t.vz1 = v[1];
  return t;
}

constexpr MaskTab MT = make_masks();
__constant__ MaskTab d_MT = make_masks();   // runtime-indexed copy (.rodata)

template <int I, int N, typename F>
__device__ __forceinline__ void static_for(F&& f) {
  if constexpr (I < N) {
    f(std::integral_constant<int, I>{});
    static_for<I + 1, N>(static_cast<F&&>(f));
  }
}

// d = co*o + cp*q (complex), packed (re,im); 4 VOP3P instrs (verified r2-r4).
__device__ __forceinline__ f32x2 ampfma(f32x2 o, f32x2 q, f32x2 co, f32x2 cp) {
  f32x2 d;
  asm("v_pk_mul_f32 %0, %2, %1 op_sel:[0,0] op_sel_hi:[0,1]\n\t"
      "v_pk_fma_f32 %0, %2, %1, %0 op_sel:[1,1,0] op_sel_hi:[1,0,1] neg_lo:[1,0,0]\n\t"
      "v_pk_fma_f32 %0, %3, %4, %0 op_sel:[0,0,0] op_sel_hi:[0,1,1]\n\t"
      "v_pk_fma_f32 %0, %3, %4, %0 op_sel:[1,1,0] op_sel_hi:[1,0,1] neg_lo:[1,0,0]"
      : "=&v"(d)
      : "v"(o), "v"(co), "v"(cp), "v"(q));
  return d;
}

__device__ __forceinline__ float fxor(float x, unsigned m) {
  return __uint_as_float(__float_as_uint(x) ^ m);
}

__device__ __forceinline__ unsigned bf16pack(float lo, float hi) {
  unsigned a = __float_as_uint(lo), b = __float_as_uint(hi);
  unsigned ra = (a + 0x7fffu + ((a >> 16) & 1u)) >> 16;   // RNE
  unsigned rb = (b + 0x7fffu + ((b >> 16) & 1u)) >> 16;
  return (ra & 0xffffu) | (rb << 16);
}

__device__ __forceinline__ unsigned cvtpk(float a, float b) {
  unsigned d;
  asm("v_cvt_pk_bf16_f32 %0, %1, %2" : "=v"(d) : "v"(a), "v"(b));
  return d;
}

__device__ __forceinline__ void gll16(const void* g, void* l) {
  __builtin_amdgcn_global_load_lds(
      (const __attribute__((address_space(1))) void*)g,
      (__attribute__((address_space(3))) void*)l, 16, 0, 0);
}

// ---------------------------------------------------------------------------
// K1 v2: basis columns e_j -> W2[j][2m+c] bf16. State in LDS (8KB/wave),
// small runtime gate loop (i-cache resident), DS-pipelined, no barriers in
// the gate loop (column private to its wave; per-wave DS ops are in-order).
// ---------------------------------------------------------------------------
__global__ __launch_bounds__(256) void build_w(const float* __restrict__ w,
                                               unsigned* __restrict__ W2u) {
  __shared__ f32x4 UL4[NGATES];
  __shared__ f32x2 S[4][DIM];

  const int tid = threadIdx.x;
  if (tid < NGATES) {
    // qml.Rot(phi, theta, omega) = RZ(omega) RY(theta) RZ(phi)
    float phi = w[tid * 3 + 0], th = w[tid * 3 + 1], om = w[tid * 3 + 2];
    float ct = cosf(th * 0.5f), st = sinf(th * 0.5f);
    float aa = (phi + om) * 0.5f, bb = (phi - om) * 0.5f;
    float cA = cosf(aa), sA = sinf(aa), cB = cosf(bb), sB = sinf(bb);
    // u00 = e^{-ia} c ; u01 = -e^{+ib} s  (u11 = conj(u00), u10 = -conj(u01))
    UL4[tid] = f32x4{ ct * cA, -ct * sA, -st * cB, -st * sB };
  }
  __syncthreads();

  const int wv = tid >> 6, lane = tid & 63;
  const int j = blockIdx.x * 4 + wv;            // 0..831
  unsigned* rowp = W2u + (size_t)j * 1024;

  if (j >= IN_DIM) {                            // zero pad rows
#pragma unroll
    for (int r = 0; r < 16; ++r) rowp[r * 64 + lane] = 0u;
    return;
  }

  f32x2* St = S[wv];
#pragma unroll
  for (int r = 0; r < 16; ++r) St[r * 64 + lane] = f32x2{0.0f, 0.0f};
  if (lane == (j & 63)) St[j].x = 1.0f;         // e_j (in-order after zeros)

  for (int g = 0; g < NGATES; ++g) {
    const f32x4 A = UL4[g];
    const unsigned v = d_MT.v[g];
    const unsigned p = d_MT.p[g];
    f32x2 nv[16];
    static_for<0, 16>([&](auto R_) {
      constexpr int r = decltype(R_)::value;
      const int m = r * 64 + lane;
      f32x2 o = St[m];
      f32x2 q = St[m ^ p];
      const unsigned sg = (unsigned)(__popc((int)((unsigned)m & v)) & 1) << 31;
      const f32x2 co = {A.x, fxor(A.y, sg)};
      const f32x2 cp = {fxor(A.z, sg), A.w};
      nv[r] = ampfma(o, q, co, cp);
    });
    static_for<0, 16>([&](auto R_) {
      constexpr int r = decltype(R_)::value;
      St[r * 64 + lane] = nv[r];
    });
  }

#pragma unroll
  for (int r = 0; r < 16; ++r) {
    f32x2 a = St[r * 64 + lane];
    rowp[r * 64 + lane] = bf16pack(a.x, a.y);
  }
}

// ---------------------------------------------------------------------------
// K2: transpose W2 [832][2048] -> W2T [2048][832] (bf16), 64x64 tiles.
// ---------------------------------------------------------------------------
__global__ __launch_bounds__(256) void transpose_w(const unsigned* __restrict__ W2u,
                                                   unsigned* __restrict__ W2Tu) {
  __shared__ unsigned tile[64][33];
  const int j0 = blockIdx.x * 64;   // gridDim.x = 13
  const int n0 = blockIdx.y * 64;   // gridDim.y = 32
  const int t = threadIdx.x;
#pragma unroll
  for (int i = 0; i < 8; ++i) {
    const int idx = i * 256 + t;
    const int jr = idx >> 5, nc = idx & 31;
    tile[jr][nc] = W2u[(size_t)(j0 + jr) * 1024 + (n0 >> 1) + nc];
  }
  __syncthreads();
#pragma unroll
  for (int i = 0; i < 8; ++i) {
    const int idx = i * 256 + t;
    const int nr = idx >> 5, jc = idx & 31;
    const unsigned lo = tile[jc * 2][nr >> 1];
    const unsigned hi = tile[jc * 2 + 1][nr >> 1];
    const unsigned sh = (unsigned)(nr & 1) * 16u;
    const unsigned val = ((lo >> sh) & 0xffffu) | (((hi >> sh) & 0xffffu) << 16);
    W2Tu[(size_t)(n0 + nr) * (KALLOC / 2) + (j0 >> 1) + jc] = val;
  }
}

// ---------------------------------------------------------------------------
// K3 v2: fused GEMM + readout. 128x128 tile, BK=32, 26 K-steps (K padded to
// 832 with zero B rows; A tail reads clamped, garbage * 0 = 0).
// global_load_lds width-16 for A (raw f32) and B (bf16); double-buffered LDS
// (2 x {A 16KB, B 8KB}); raw s_barrier + counted vmcnt(6) (loads 2-deep in
// flight, never drained mid-loop). Source-swizzled LDS (rule #21):
//   A: chunk c' = c ^ (row&7)      -> frag reads 2-way (free)
//   B: chunk c' = c ^ ((row>>1)&3) -> frag reads 2-way (free)
// A frags convert f32->bf16 at read via v_cvt_pk_bf16_f32 (1 instr/pair).
// ---------------------------------------------------------------------------
__global__ __launch_bounds__(256) void gemm_fused(const float* __restrict__ X,
                                                  const unsigned short* __restrict__ W2T,
                                                  float* __restrict__ accb) {
  __shared__ u32x4 lds4[3072];   // 48 KB
  char* lds = (char*)lds4;

  const int tid = threadIdx.x;
  const int orig = blockIdx.x;
  const int bx = (orig & 7) * 256 + (orig >> 3);   // XCD-chunked (2048%8==0)
  const int mb = bx >> 4, nb = bx & 15;
  const int m0 = mb * 128, n0 = nb * 128;
  const int lane = tid & 63, wv = tid >> 6;
  const int wm = wv >> 1, wn = wv & 1;

  const char* Xb = (const char*)X;
  const char* Bsrc = (const char*)W2T;
  const long XMAXB = (long)16384 * 784 * 4 - 16;

  auto stage = [&](int t) {
    char* Ab = lds + (t & 1) * 24576;
    char* Bb = Ab + 16384;
#pragma unroll
    for (int i = 0; i < 4; ++i) {                 // A: 4 instrs x 8 rows
      const int g = wv * 4 + i;
      const int row = g * 8 + (lane >> 3);
      const int c = (lane & 7) ^ (row & 7);
      long off = ((long)(m0 + row) * 784 + t * 32 + c * 4) * 4;
      off = off < XMAXB ? off : XMAXB;
      gll16(Xb + off, Ab + g * 1024);
    }
#pragma unroll
    for (int i = 0; i < 2; ++i) {                 // B: 2 instrs x 16 rows
      const int g = wv * 2 + i;
      const int row = g * 16 + (lane >> 2);
      const int c = (lane & 3) ^ ((row >> 1) & 3);
      gll16(Bsrc + (long)(n0 + row) * (KALLOC * 2) + t * 64 + c * 16,
            Bb + g * 1024);
    }
  };

  stage(0);
  stage(1);
  asm volatile("s_waitcnt vmcnt(6)" ::: "memory");   // tile0 landed
  __builtin_amdgcn_s_barrier();

  f32x4 acc[4][4];
#pragma unroll
  for (int fm = 0; fm < 4; ++fm)
#pragma unroll
    for (int fn = 0; fn < 4; ++fn) acc[fm][fn] = f32x4{0, 0, 0, 0};

  for (int t = 0; t < 26; ++t) {
    const char* Ab = lds + (t & 1) * 24576;
    const char* Bb = Ab + 16384;

    bf16x8 af[4], bfr[4];
#pragma unroll
    for (int f = 0; f < 4; ++f) {
      const int ar = wm * 64 + f * 16 + (lane & 15);
      const int c0 = (lane >> 4) * 2;
      f32x4 v0 = *(const f32x4*)(Ab + ar * 128 + ((c0 ^ (ar & 7)) * 16));
      f32x4 v1 = *(const f32x4*)(Ab + ar * 128 + (((c0 + 1) ^ (ar & 7)) * 16));
      union { u32x4 u; bf16x8 h; } cv;
      cv.u = u32x4{cvtpk(v0.x, v0.y), cvtpk(v0.z, v0.w),
                   cvtpk(v1.x, v1.y), cvtpk(v1.z, v1.w)};
      af[f] = cv.h;
      const int br = wn * 64 + f * 16 + (lane & 15);
      const int bc = (lane >> 4) ^ ((br >> 1) & 3);
      bfr[f] = *(const bf16x8*)(Bb + br * 64 + bc * 16);
    }
    asm volatile("s_waitcnt lgkmcnt(0)" ::: "memory");  // my LDS reads done
    __builtin_amdgcn_sched_barrier(0);
    __builtin_amdgcn_s_barrier();                       // all waves done reading
    __builtin_amdgcn_sched_barrier(0);
    if (t < 24) stage(t + 2);                           // refill this buffer
    __builtin_amdgcn_sched_barrier(0);

#pragma unroll
    for (int fm = 0; fm < 4; ++fm)
#pragma unroll
      for (int fn = 0; fn < 4; ++fn)
        acc[fm][fn] = __builtin_amdgcn_mfma_f32_16x16x32_bf16(
            af[fm], bfr[fn], acc[fm][fn], 0, 0, 0);

    if (t < 24) asm volatile("s_waitcnt vmcnt(6)" ::: "memory");
    else        asm volatile("s_waitcnt vmcnt(0)" ::: "memory");
    __builtin_amdgcn_s_barrier();                       // next buffer ready
  }

  // ---- epilogue: per-sample (n2, z0, z1) partials (verified r4) ----
  constexpr unsigned vz0 = MT.vz0, vz1 = MT.vz1;
  const int colbase = n0 + wn * 64 + (lane & 15);
#pragma unroll
  for (int fm = 0; fm < 4; ++fm) {
    float sn[4] = {0, 0, 0, 0}, s0[4] = {0, 0, 0, 0}, s1[4] = {0, 0, 0, 0};
#pragma unroll
    for (int fn = 0; fn < 4; ++fn) {
      const int st = (colbase + fn * 16) >> 1;     // quantum state index
      const float g0 = 1.0f - 2.0f * (float)(__popc(st & (int)vz0) & 1);
      const float g1 = 1.0f - 2.0f * (float)(__popc(st & (int)vz1) & 1);
#pragma unroll
      for (int r = 0; r < 4; ++r) {
        const float vv = acc[fm][fn][r];
        const float wq = vv * vv;
        sn[r] += wq;
        s0[r] = fmaf(g0, wq, s0[r]);
        s1[r] = fmaf(g1, wq, s1[r]);
      }
    }
#pragma unroll
    for (int off = 1; off < 16; off <<= 1) {
#pragma unroll
      for (int r = 0; r < 4; ++r) {
        sn[r] += __shfl_xor(sn[r], off);
        s0[r] += __shfl_xor(s0[r], off);
        s1[r] += __shfl_xor(s1[r], off);
      }
    }
    if ((lane & 15) == 0) {
#pragma unroll
      for (int r = 0; r < 4; ++r) {
        const int m = m0 + wm * 64 + fm * 16 + (lane >> 4) * 4 + r;
        *(f32x4*)(accb + ((size_t)nb * BATCH + m) * 4) =
            f32x4{sn[r], s0[r], s1[r], 0.0f};
      }
    }
  }
}

// ---------------------------------------------------------------------------
// K4/K5: per-sample loss + mean reduction.
// ---------------------------------------------------------------------------
__global__ __launch_bounds__(256) void loss_partial(const float* __restrict__ accb,
                                                    const int* __restrict__ y,
                                                    float* __restrict__ partial) {
  const int s = blockIdx.x * 256 + threadIdx.x;
  float n2 = 0.0f, z0 = 0.0f, z1 = 0.0f;
#pragma unroll
  for (int nb = 0; nb < 16; ++nb) {
    f32x4 v = *(const f32x4*)(accb + ((size_t)nb * BATCH + s) * 4);
    n2 += v.x; z0 += v.y; z1 += v.z;
  }
  const float inv = 1.0f / n2;
  const float l0 = z0 * inv, l1 = z1 * inv;
  const float mx = fmaxf(l0, l1);
  const float lse = mx + logf(expf(l0 - mx) + expf(l1 - mx));
  float loss = lse - ((y[s] == 0) ? l0 : l1);

  __shared__ float sm[256];
  sm[threadIdx.x] = loss;
  __syncthreads();
  for (int st = 128; st > 0; st >>= 1) {
    if (threadIdx.x < st) sm[threadIdx.x] += sm[threadIdx.x + st];
    __syncthreads();
  }
  if (threadIdx.x == 0) partial[blockIdx.x] = sm[0];
}

__global__ __launch_bounds__(64) void loss_final(const float* __restrict__ partial,
                                                 float* __restrict__ out) {
  float v = partial[threadIdx.x];
#pragma unroll
  for (int off = 1; off < 64; off <<= 1) v += __shfl_xor(v, off);
  if (threadIdx.x == 0) out[0] = v * (1.0f / (float)BATCH);
}

// ---------------------------------------------------------------------------
extern "C" void kernel_launch(void* const* d_in, const int* in_sizes, int n_in,
                              void* d_out, int out_size, void* d_ws, size_t ws_size,
                              hipStream_t stream) {
  const float* x = (const float*)d_in[0];   // [16384, 784] f32
  const float* w = (const float*)d_in[1];   // [5, 10, 3] f32
  const int*   y = (const int*)d_in[2];     // [16384] i32

  char* ws = (char*)d_ws;
  unsigned* W2u  = (unsigned*)ws;                    // 832*1024 u32 = 3.41 MB
  unsigned* W2Tu = (unsigned*)(ws + 3407872);        // 2048*416 u32 = 3.41 MB
  float*    accb = (float*)(ws + 6815744);           // 16*16384*4 f32 = 4 MB
  float* partial = (float*)(ws + 11010048);          // 64 f32

  build_w<<<KALLOC / 4, 256, 0, stream>>>(w, W2u);
  transpose_w<<<dim3(13, 32), 256, 0, stream>>>(W2u, W2Tu);
  gemm_fused<<<2048, 256, 0, stream>>>(x, (const unsigned short*)W2Tu, accb);
  loss_partial<<<BATCH / 256, 256, 0, stream>>>(accb, y, partial);
  loss_final<<<1, 64, 0, stream>>>(partial, (float*)d_out);
}

// Round 6
// 119.358 us; speedup vs baseline: 2.3895x; 1.2415x over previous
//
#include <hip/hip_runtime.h>
#include <type_traits>

#define NQ 10
#define N_DEPTH 5
#define DIM 1024
#define BATCH 16384
#define IN_DIM 784
#define NGATES 50
#define KPAD 800      // GEMM K extent (25*32); Xb/W2T cols >=784 are zero
#define KALLOC 832    // W2 row allocation (13*64 transpose tiles)
#define NK 25         // K-steps of 32

typedef float f32x2 __attribute__((ext_vector_type(2)));
typedef float f32x4 __attribute__((ext_vector_type(4)));
typedef short bf16x8 __attribute__((ext_vector_type(8)));
typedef unsigned u32x4 __attribute__((ext_vector_type(4)));

// ---------------------------------------------------------------------------
// Compile-time mask tables: CNOTs absorbed into GF(2)-linear index transform.
// ---------------------------------------------------------------------------
struct MaskTab {
  unsigned v[NGATES];
  unsigned p[NGATES];
  unsigned vz0, vz1;
};

constexpr MaskTab make_masks() {
  MaskTab t{};
  unsigned v[NQ], p[NQ];
  for (int i = 0; i < NQ; ++i) { v[i] = 1u << (9 - i); p[i] = 1u << (9 - i); }
  for (int d = 0; d < N_DEPTH; ++d) {
    for (int i = 0; i < NQ; ++i) {
      int c = i, tt = (i + 1) % NQ;
      v[tt] ^= v[c];
      p[c]  ^= p[tt];
    }
    for (int i = 0; i < NQ; ++i) {
      t.v[d * NQ + i] = v[i];
      t.p[d * NQ + i] = p[i];
    }
  }
  t.vz0 = v[0];
  t.vz1 = v[1];
  return t;
}

constexpr MaskTab MT = make_masks();
__constant__ MaskTab d_MT = make_masks();

// d = co*o + cp*q (complex), packed (re,im); 4 VOP3P instrs (verified r2-r5).
__device__ __forceinline__ f32x2 ampfma(f32x2 o, f32x2 q, f32x2 co, f32x2 cp) {
  f32x2 d;
  asm("v_pk_mul_f32 %0, %2, %1 op_sel:[0,0] op_sel_hi:[0,1]\n\t"
      "v_pk_fma_f32 %0, %2, %1, %0 op_sel:[1,1,0] op_sel_hi:[1,0,1] neg_lo:[1,0,0]\n\t"
      "v_pk_fma_f32 %0, %3, %4, %0 op_sel:[0,0,0] op_sel_hi:[0,1,1]\n\t"
      "v_pk_fma_f32 %0, %3, %4, %0 op_sel:[1,1,0] op_sel_hi:[1,0,1] neg_lo:[1,0,0]"
      : "=&v"(d)
      : "v"(o), "v"(co), "v"(cp), "v"(q));
  return d;
}

__device__ __forceinline__ float fxor(float x, unsigned m) {
  return __uint_as_float(__float_as_uint(x) ^ m);
}

__device__ __forceinline__ unsigned bf16pack(float lo, float hi) {
  unsigned a = __float_as_uint(lo), b = __float_as_uint(hi);
  unsigned ra = (a + 0x7fffu + ((a >> 16) & 1u)) >> 16;   // RNE
  unsigned rb = (b + 0x7fffu + ((b >> 16) & 1u)) >> 16;
  return (ra & 0xffffu) | (rb << 16);
}

__device__ __forceinline__ unsigned cvtpk(float a, float b) {
  unsigned d;
  asm("v_cvt_pk_bf16_f32 %0, %1, %2" : "=v"(d) : "v"(a), "v"(b));
  return d;
}

__device__ __forceinline__ void gll16(const void* g, void* l) {
  __builtin_amdgcn_global_load_lds(
      (const __attribute__((address_space(1))) void*)g,
      (__attribute__((address_space(3))) void*)l, 16, 0, 0);
}

// ---------------------------------------------------------------------------
// K0: X f32 [16384][784] -> Xb bf16 [16384][800] (cols 784..799 zero).
// ---------------------------------------------------------------------------
__global__ __launch_bounds__(256) void xcvt(const float* __restrict__ X,
                                            unsigned* __restrict__ Xb) {
  const int cid = blockIdx.x * 256 + threadIdx.x;   // 16384*100 chunk tasks
  if (cid >= 16384 * 100) return;
  const int row = cid / 100, c8 = cid - row * 100;
  u32x4 out;
  if (c8 < 98) {
    const float* src = X + (size_t)row * IN_DIM + c8 * 8;
    f32x4 v0 = *(const f32x4*)src;
    f32x4 v1 = *(const f32x4*)(src + 4);
    out = u32x4{cvtpk(v0.x, v0.y), cvtpk(v0.z, v0.w),
                cvtpk(v1.x, v1.y), cvtpk(v1.z, v1.w)};
  } else {
    out = u32x4{0, 0, 0, 0};
  }
  *(u32x4*)(Xb + (size_t)row * (KPAD / 2) + c8 * 4) = out;
}

// ---------------------------------------------------------------------------
// K1 v3: basis columns e_j -> W2[j][2m+c] bf16. One column per 256-thread
// block (4 waves cooperate); state ping-pongs between two LDS buffers, one
// barrier per gate. 832 blocks -> 3328 waves (vs 832 in v2).
// ---------------------------------------------------------------------------
__global__ __launch_bounds__(256) void build_w(const float* __restrict__ w,
                                               unsigned* __restrict__ W2u) {
  __shared__ f32x4 UL4[NGATES];
  __shared__ f32x2 S0[DIM];
  __shared__ f32x2 S1[DIM];

  const int tid = threadIdx.x;
  if (tid < NGATES) {
    // qml.Rot(phi, theta, omega) = RZ(omega) RY(theta) RZ(phi)
    float phi = w[tid * 3 + 0], th = w[tid * 3 + 1], om = w[tid * 3 + 2];
    float ct = cosf(th * 0.5f), st = sinf(th * 0.5f);
    float aa = (phi + om) * 0.5f, bb = (phi - om) * 0.5f;
    float cA = cosf(aa), sA = sinf(aa), cB = cosf(bb), sB = sinf(bb);
    // u00 = e^{-ia} c ; u01 = -e^{+ib} s  (u11 = conj(u00), u10 = -conj(u01))
    UL4[tid] = f32x4{ ct * cA, -ct * sA, -st * cB, -st * sB };
  }

  const int j = blockIdx.x;                     // 0..831
  unsigned* rowp = W2u + (size_t)j * 1024;

  if (j >= IN_DIM) {                            // zero pad rows (uniform branch)
#pragma unroll
    for (int k = 0; k < 4; ++k) rowp[tid + k * 256] = 0u;
    return;
  }

#pragma unroll
  for (int k = 0; k < 4; ++k) {
    const int m = tid + k * 256;
    S0[m] = f32x2{(m == j) ? 1.0f : 0.0f, 0.0f};
  }
  __syncthreads();

  for (int g = 0; g < NGATES; ++g) {
    const f32x2* src = (g & 1) ? S1 : S0;
    f32x2* dst = (g & 1) ? S0 : S1;
    const f32x4 A = UL4[g];
    const unsigned v = d_MT.v[g];
    const unsigned p = d_MT.p[g];
#pragma unroll
    for (int k = 0; k < 4; ++k) {
      const int m = tid + k * 256;
      f32x2 o = src[m];
      f32x2 q = src[m ^ (int)p];
      const unsigned sg = (unsigned)(__popc((int)((unsigned)m & v)) & 1) << 31;
      const f32x2 co = {A.x, fxor(A.y, sg)};
      const f32x2 cp = {fxor(A.z, sg), A.w};
      dst[m] = ampfma(o, q, co, cp);
    }
    __syncthreads();
  }

  const f32x2* fin = S0;   // 50 gates (even) -> final state back in S0
#pragma unroll
  for (int k = 0; k < 4; ++k) {
    const int m = tid + k * 256;
    f32x2 a = fin[m];
    rowp[m] = bf16pack(a.x, a.y);
  }
}

// ---------------------------------------------------------------------------
// K2: transpose W2 [832][2048] -> W2T [2048][832] (bf16), 64x64 tiles.
// ---------------------------------------------------------------------------
__global__ __launch_bounds__(256) void transpose_w(const unsigned* __restrict__ W2u,
                                                   unsigned* __restrict__ W2Tu) {
  __shared__ unsigned tile[64][33];
  const int j0 = blockIdx.x * 64;   // gridDim.x = 13
  const int n0 = blockIdx.y * 64;   // gridDim.y = 32
  const int t = threadIdx.x;
#pragma unroll
  for (int i = 0; i < 8; ++i) {
    const int idx = i * 256 + t;
    const int jr = idx >> 5, nc = idx & 31;
    tile[jr][nc] = W2u[(size_t)(j0 + jr) * 1024 + (n0 >> 1) + nc];
  }
  __syncthreads();
#pragma unroll
  for (int i = 0; i < 8; ++i) {
    const int idx = i * 256 + t;
    const int nr = idx >> 5, jc = idx & 31;
    const unsigned lo = tile[jc * 2][nr >> 1];
    const unsigned hi = tile[jc * 2 + 1][nr >> 1];
    const unsigned sh = (unsigned)(nr & 1) * 16u;
    const unsigned val = ((lo >> sh) & 0xffffu) | (((hi >> sh) & 0xffffu) << 16);
    W2Tu[(size_t)(n0 + nr) * (KALLOC / 2) + (j0 >> 1) + jc] = val;
  }
}

// ---------------------------------------------------------------------------
// K3 v3: fused GEMM + readout. 256x256 tile, 8 waves (2M x 4N, 128x64/wave),
// BK=32, 25 K-steps, all-bf16. LDS 2 x (A 16KB + B 16KB) = 64KB dbuf.
// gll16 staging with pre-swizzled SOURCE (rule #21): LDS (row, c') holds
// global chunk c = c' ^ ((row>>1)&3); frag reads apply the same XOR ->
// 2-way banks (free). Counted vmcnt(4), raw s_barrier, setprio on MFMA.
// ---------------------------------------------------------------------------
__global__ __launch_bounds__(512) void gemm_fused(const unsigned short* __restrict__ Xb,
                                                  const unsigned short* __restrict__ W2T,
                                                  float* __restrict__ accb) {
  __shared__ u32x4 lds4[4096];   // 64 KB
  char* lds = (char*)lds4;

  const int tid = threadIdx.x;
  const int orig = blockIdx.x;                    // 512 blocks
  const int bx = (orig & 7) * 64 + (orig >> 3);   // XCD-chunked (512%8==0)
  const int mb = bx >> 3, nb = bx & 7;
  const int m0 = mb * 256, n0 = nb * 256;
  const int lane = tid & 63, wv = tid >> 6;
  const int wm = wv >> 2, wn = wv & 3;

  auto stage = [&](int t) {
    char* Ab = lds + (t & 1) * 32768;
    char* Bb = Ab + 16384;
    // lane l of instr g: LDS row = g*16 + (l>>2), chunk' = l&3,
    // sourced from global chunk c = (l&3) ^ ((l>>3)&3).
    const int lrow = lane >> 2;
    const int c = (lane & 3) ^ ((lane >> 3) & 3);
#pragma unroll
    for (int i = 0; i < 2; ++i) {                 // A: 2 instrs/wave
      const int g = wv * 2 + i;
      const int row = g * 16 + lrow;
      gll16(Xb + (size_t)(m0 + row) * KPAD + t * 32 + c * 8, Ab + g * 1024);
    }
#pragma unroll
    for (int i = 0; i < 2; ++i) {                 // B: 2 instrs/wave
      const int g = wv * 2 + i;
      const int row = g * 16 + lrow;
      gll16(W2T + (size_t)(n0 + row) * KALLOC + t * 32 + c * 8, Bb + g * 1024);
    }
  };

  stage(0);
  stage(1);
  asm volatile("s_waitcnt vmcnt(4)" ::: "memory");   // tile0 landed
  __builtin_amdgcn_s_barrier();

  f32x4 acc[8][4];
#pragma unroll
  for (int fm = 0; fm < 8; ++fm)
#pragma unroll
    for (int fn = 0; fn < 4; ++fn) acc[fm][fn] = f32x4{0, 0, 0, 0};

  for (int t = 0; t < NK; ++t) {
    const char* Ab = lds + (t & 1) * 32768;
    const char* Bb = Ab + 16384;
    const int kc = lane >> 4;                      // k-chunk 0..3

    bf16x8 af[8], bfr[4];
#pragma unroll
    for (int f = 0; f < 8; ++f) {
      const int ar = wm * 128 + f * 16 + (lane & 15);
      af[f] = *(const bf16x8*)(Ab + ar * 64 + ((kc ^ ((ar >> 1) & 3)) * 16));
    }
#pragma unroll
    for (int f = 0; f < 4; ++f) {
      const int br = wn * 64 + f * 16 + (lane & 15);
      bfr[f] = *(const bf16x8*)(Bb + br * 64 + ((kc ^ ((br >> 1) & 3)) * 16));
    }
    asm volatile("s_waitcnt lgkmcnt(0)" ::: "memory");
    __builtin_amdgcn_sched_barrier(0);
    __builtin_amdgcn_s_barrier();                  // all waves done reading
    __builtin_amdgcn_sched_barrier(0);
    if (t < NK - 2) stage(t + 2);                  // refill this buffer
    __builtin_amdgcn_sched_barrier(0);

    __builtin_amdgcn_s_setprio(1);
#pragma unroll
    for (int fm = 0; fm < 8; ++fm)
#pragma unroll
      for (int fn = 0; fn < 4; ++fn)
        acc[fm][fn] = __builtin_amdgcn_mfma_f32_16x16x32_bf16(
            af[fm], bfr[fn], acc[fm][fn], 0, 0, 0);
    __builtin_amdgcn_s_setprio(0);

    if (t < NK - 2) asm volatile("s_waitcnt vmcnt(4)" ::: "memory");
    else            asm volatile("s_waitcnt vmcnt(0)" ::: "memory");
    __builtin_amdgcn_s_barrier();                  // next buffer ready
  }

  // ---- epilogue: per-sample (n2, z0, z1) partials (verified r4/r5) ----
  constexpr unsigned vz0 = MT.vz0, vz1 = MT.vz1;
  const int colbase = n0 + wn * 64 + (lane & 15);
#pragma unroll
  for (int fm = 0; fm < 8; ++fm) {
    float sn[4] = {0, 0, 0, 0}, s0[4] = {0, 0, 0, 0}, s1[4] = {0, 0, 0, 0};
#pragma unroll
    for (int fn = 0; fn < 4; ++fn) {
      const int st = (colbase + fn * 16) >> 1;     // quantum state index
      const float g0 = 1.0f - 2.0f * (float)(__popc(st & (int)vz0) & 1);
      const float g1 = 1.0f - 2.0f * (float)(__popc(st & (int)vz1) & 1);
#pragma unroll
      for (int r = 0; r < 4; ++r) {
        const float vv = acc[fm][fn][r];
        const float wq = vv * vv;
        sn[r] += wq;
        s0[r] = fmaf(g0, wq, s0[r]);
        s1[r] = fmaf(g1, wq, s1[r]);
      }
    }
#pragma unroll
    for (int off = 1; off < 16; off <<= 1) {
#pragma unroll
      for (int r = 0; r < 4; ++r) {
        sn[r] += __shfl_xor(sn[r], off);
        s0[r] += __shfl_xor(s0[r], off);
        s1[r] += __shfl_xor(s1[r], off);
      }
    }
    if ((lane & 15) == 0) {
#pragma unroll
      for (int r = 0; r < 4; ++r) {
        const int m = m0 + wm * 128 + fm * 16 + (lane >> 4) * 4 + r;
        *(f32x4*)(accb + ((size_t)nb * BATCH + m) * 4) =
            f32x4{sn[r], s0[r], s1[r], 0.0f};
      }
    }
  }
}

// ---------------------------------------------------------------------------
// K4/K5: per-sample loss + mean reduction.
// ---------------------------------------------------------------------------
__global__ __launch_bounds__(256) void loss_partial(const float* __restrict__ accb,
                                                    const int* __restrict__ y,
                                                    float* __restrict__ partial) {
  const int s = blockIdx.x * 256 + threadIdx.x;
  float n2 = 0.0f, z0 = 0.0f, z1 = 0.0f;
#pragma unroll
  for (int nb = 0; nb < 8; ++nb) {
    f32x4 v = *(const f32x4*)(accb + ((size_t)nb * BATCH + s) * 4);
    n2 += v.x; z0 += v.y; z1 += v.z;
  }
  const float inv = 1.0f / n2;
  const float l0 = z0 * inv, l1 = z1 * inv;
  const float mx = fmaxf(l0, l1);
  const float lse = mx + logf(expf(l0 - mx) + expf(l1 - mx));
  float loss = lse - ((y[s] == 0) ? l0 : l1);

  __shared__ float sm[256];
  sm[threadIdx.x] = loss;
  __syncthreads();
  for (int st = 128; st > 0; st >>= 1) {
    if (threadIdx.x < st) sm[threadIdx.x] += sm[threadIdx.x + st];
    __syncthreads();
  }
  if (threadIdx.x == 0) partial[blockIdx.x] = sm[0];
}

__global__ __launch_bounds__(64) void loss_final(const float* __restrict__ partial,
                                                 float* __restrict__ out) {
  float v = partial[threadIdx.x];
#pragma unroll
  for (int off = 1; off < 64; off <<= 1) v += __shfl_xor(v, off);
  if (threadIdx.x == 0) out[0] = v * (1.0f / (float)BATCH);
}

// ---------------------------------------------------------------------------
extern "C" void kernel_launch(void* const* d_in, const int* in_sizes, int n_in,
                              void* d_out, int out_size, void* d_ws, size_t ws_size,
                              hipStream_t stream) {
  const float* x = (const float*)d_in[0];   // [16384, 784] f32
  const float* w = (const float*)d_in[1];   // [5, 10, 3] f32
  const int*   y = (const int*)d_in[2];     // [16384] i32

  char* ws = (char*)d_ws;
  unsigned* Xb   = (unsigned*)ws;                    // 16384*800*2 = 26.2 MB
  unsigned* W2u  = (unsigned*)(ws + 26214400);       // 832*1024*4  = 3.41 MB
  unsigned* W2Tu = (unsigned*)(ws + 29622272);       // 2048*832*2  = 3.41 MB
  float*    accb = (float*)(ws + 26214400);          // 2 MB, reuses W2u region
  float* partial = (float*)(ws + 33030144);          // 64 f32

  xcvt<<<6400, 256, 0, stream>>>(x, Xb);
  build_w<<<KALLOC, 256, 0, stream>>>(w, W2u);
  transpose_w<<<dim3(13, 32), 256, 0, stream>>>(W2u, W2Tu);
  gemm_fused<<<512, 512, 0, stream>>>((const unsigned short*)Xb,
                                      (const unsigned short*)W2Tu, accb);
  loss_partial<<<BATCH / 256, 256, 0, stream>>>(accb, y, partial);
  loss_final<<<1, 64, 0, stream>>>(partial, (float*)d_out);
}